// Round 5
// baseline (269.912 us; speedup 1.0000x reference)
//
#include <hip/hip_runtime.h>
#include <hip/hip_bf16.h>
#include <cstdint>

// CrossAttentionMultiHead: B=8, C=512, H=W=64 (S=4096), L=77, E=768, heads=4 (dh=128), GN groups=8.
// FP32 I/O; attention_mask int32. Compute in bf16 MFMA, fp32 accum.
// R5: k2 single 53.2KB LDS arena (3 blocks/CU), global_load_lds async staging w/ source-XOR
//     swizzle, Kh direct-from-global fragments; k1 LDS-free direct-fragment GEMM.

typedef __attribute__((ext_vector_type(8))) short short8;
typedef __attribute__((ext_vector_type(4))) short short4v;
typedef __attribute__((ext_vector_type(4))) float f32x4;

#define DEV __device__ __forceinline__

DEV float bf2f(unsigned short u){ union{uint32_t i; float f;} x; x.i = ((uint32_t)u) << 16; return x.f; }
DEV unsigned short f2bf(float f){ __hip_bfloat16 h = __float2bfloat16(f); return *reinterpret_cast<unsigned short*>(&h); }
DEV short8 ld8(const unsigned short* p){ return *reinterpret_cast<const short8*>(p); }
DEV f32x4 ldf4(const float* p){ return *reinterpret_cast<const f32x4*>(p); }

#if defined(__has_builtin)
#if __has_builtin(__builtin_amdgcn_global_load_lds)
#define HAVE_ASYNC_LDS 1
#endif
#endif

// ---------------------------------------------------------------- k_prep: Wq fp32 -> bf16
__global__ __launch_bounds__(256) void k_prep(const float* __restrict__ Wq,
                                              unsigned short* __restrict__ wsWq){
  int i = (blockIdx.x * 256 + threadIdx.x) * 4;
  f32x4 v = ldf4(&Wq[i]);
  short4v o;
  #pragma unroll
  for (int j = 0; j < 4; ++j) o[j] = (short)f2bf(v[j]);
  *reinterpret_cast<short4v*>(&wsWq[i]) = o;
}

// ---------------------------------------------------------------- k0: x[b][c][s] fp32 -> xT[bz][s-s_base][c] bf16
__global__ __launch_bounds__(256) void k0_transpose(const float* __restrict__ x,
                                                    unsigned short* __restrict__ xT,
                                                    int b0, int s_base, int slen){
  __shared__ unsigned short t[64 * 72];          // 64x64 tile, stride 72, XOR-swizzled s-octets
  const int tid = threadIdx.x;
  const int s0 = s_base + blockIdx.x * 64, c0 = blockIdx.y * 64, bz = blockIdx.z;
  const int bg = b0 + bz;
  #pragma unroll
  for (int it = 0; it < 2; ++it){
    int slot = tid + it * 256;                   // 512 slots = 64 c-rows x 8 s-octets
    int r = slot >> 3, sg = slot & 7;
    int sw = sg ^ (r >> 3);
    const float* src = &x[((size_t)(bg * 512 + c0 + r)) * 4096 + s0 + sg * 8];
    f32x4 a = ldf4(src), b = ldf4(src + 4);
    short8 v;
    #pragma unroll
    for (int j = 0; j < 4; ++j){ v[j] = (short)f2bf(a[j]); v[j + 4] = (short)f2bf(b[j]); }
    *reinterpret_cast<short8*>(&t[r * 72 + sw * 8]) = v;
  }
  __syncthreads();
  #pragma unroll
  for (int it = 0; it < 2; ++it){
    int slot = tid + it * 256;                   // 512 slots = 64 s-rows x 8 c-octets
    int j = slot >> 3, i8 = slot & 7;
    short8 v;
    #pragma unroll
    for (int q = 0; q < 8; ++q){
      int c = i8 * 8 + q;
      int sw = (j >> 3) ^ i8;
      v[q] = (short)t[c * 72 + sw * 8 + (j & 7)];
    }
    *reinterpret_cast<short8*>(&xT[((size_t)(bz * slen) + blockIdx.x * 64 + j) * 512 + c0 + i8 * 8]) = v;
  }
}

// ---------------------------------------------------------------- k1: direct-fragment GEMM, no LDS, no barriers
// block (uc, bz): out[80l x 64u]; 4 waves split N=64 into 16 cols each.
// u-chunks 0..7 -> K, 8..15 -> V.
__global__ __launch_bounds__(256) void k1_kvproj(const float* __restrict__ text,
                                                 const float* __restrict__ Wk,
                                                 const float* __restrict__ Wkb,
                                                 const float* __restrict__ Wv,
                                                 const float* __restrict__ Wvb,
                                                 unsigned short* __restrict__ wsK,
                                                 unsigned short* __restrict__ wsVt,
                                                 int b0){
  const int tid = threadIdx.x, wave = tid >> 6, lane = tid & 63;
  const int m16 = lane & 15, quad = lane >> 4;
  const int uc = blockIdx.x, bz = blockIdx.y, bg = b0 + bz;
  const int u0 = uc * 64;
  const bool isK = (u0 < 512);
  const float* W  = isK ? Wk  : Wv;
  const float* Wb = isK ? Wkb : Wvb;
  const int c = (u0 & 511) + wave * 16 + m16;    // this lane's output column
  f32x4 acc[5];
  #pragma unroll
  for (int mt = 0; mt < 5; ++mt) acc[mt] = (f32x4){0.f, 0.f, 0.f, 0.f};
  const float* wrow = &W[(size_t)c * 768];
  const float* tb   = &text[(size_t)(bg * 77) * 768];
  #pragma unroll 2
  for (int e0 = 0; e0 < 768; e0 += 32){
    const int e = e0 + quad * 8;
    short8 bf_;
    {
      f32x4 w0 = ldf4(&wrow[e]), w1 = ldf4(&wrow[e + 4]);
      #pragma unroll
      for (int j = 0; j < 4; ++j){ bf_[j] = (short)f2bf(w0[j]); bf_[j + 4] = (short)f2bf(w1[j]); }
    }
    #pragma unroll
    for (int mt = 0; mt < 5; ++mt){
      int l = mt * 16 + m16;
      short8 af_ = {};
      if (l < 77){
        f32x4 a0 = ldf4(&tb[(size_t)l * 768 + e]), a1 = ldf4(&tb[(size_t)l * 768 + e + 4]);
        #pragma unroll
        for (int j = 0; j < 4; ++j){ af_[j] = (short)f2bf(a0[j]); af_[j + 4] = (short)f2bf(a1[j]); }
      }
      acc[mt] = __builtin_amdgcn_mfma_f32_16x16x32_bf16(af_, bf_, acc[mt], 0, 0, 0);
    }
  }
  const float bias = Wb[c];
  if (isK){
    #pragma unroll
    for (int mt = 0; mt < 5; ++mt)
      #pragma unroll
      for (int r = 0; r < 4; ++r){
        int l = mt * 16 + quad * 4 + r;
        if (l < 77) wsK[((size_t)(bz * 77 + l)) * 512 + c] = f2bf(acc[mt][r] + bias);
      }
  } else {
    #pragma unroll
    for (int mt = 0; mt < 5; ++mt){
      short4v pk;
      #pragma unroll
      for (int r = 0; r < 4; ++r) pk[r] = (short)f2bf(acc[mt][r] + bias);
      *reinterpret_cast<short4v*>(&wsVt[((size_t)(bz * 512 + c)) * 80 + mt * 16 + quad * 4]) = pk;
    }
  }
}

// ---------------------------------------------------------------- k2: fused Qproj + attention
// LDS arena (53248 B), phase-aliased:
//   phase1: A[128][64] @0 + B[128][64] @8192 (shorts)  [async-staged, source-XOR swizzle]
//   phase2: Qt[128][136] @0
//   phase3: Pt[128][104] @0 + Vt[128][104] @13312
__global__ __launch_bounds__(256, 3) void k2_attn(const unsigned short* __restrict__ xT,
                                                  const unsigned short* __restrict__ wsK,
                                                  const unsigned short* __restrict__ wsVt,
                                                  const int* __restrict__ amask,
                                                  const unsigned short* __restrict__ wsWq,
                                                  const float* __restrict__ Wqb,
                                                  float* __restrict__ out,
                                                  float* __restrict__ gnacc,
                                                  int b0, int s_base, int slen){
  __shared__ unsigned short arena[26624];
  __shared__ float maskf[96];
  unsigned short* ldsA = arena;
  unsigned short* ldsB = arena + 8192;
  unsigned short* Qt   = arena;
  unsigned short* Pt   = arena;
  unsigned short* Vt   = arena + 13312;

  const int tid = threadIdx.x;
  const int wave = tid >> 6, lane = tid & 63;
  const int m16 = lane & 15, quad = lane >> 4;
  const int st = blockIdx.x, h = blockIdx.y, bz = blockIdx.z;
  const int bg = b0 + bz;
  const int s_glob = s_base + st * 128;
  const int R0 = (wave >> 1) * 64, C0 = (wave & 1) * 64;

  if (tid < 96){
    int l = tid;
    float mbv = -30000.f;
    if (l < 77 && amask[bg * 77 + l] != 0) mbv = 0.f;
    maskf[l] = mbv;
  }

  // ---- phase 1: Qt = Wq_h[128x512] @ x[512 x 128s], BK=64, async staging
  f32x4 acc[4][4];
  #pragma unroll
  for (int mt = 0; mt < 4; ++mt)
    #pragma unroll
    for (int nt = 0; nt < 4; ++nt) acc[mt][nt] = (f32x4){0.f, 0.f, 0.f, 0.f};
  const unsigned short* Aglob = wsWq + (size_t)(h * 128) * 512;
  const unsigned short* Bglob = xT + ((size_t)bz * slen + st * 128) * 512;
  const int slot0 = tid, srow = slot0 >> 3, sc8g = (slot0 & 7) ^ (srow & 7);
  for (int kc = 0; kc < 8; ++kc){
    #pragma unroll
    for (int it = 0; it < 4; ++it){
      int slot = tid + it * 256;
      int row = slot >> 3;
      int sc8 = (slot & 7) ^ (row & 7);          // source-XOR swizzle
      const unsigned short* ga = &Aglob[(size_t)row * 512 + kc * 64 + sc8 * 8];
#ifdef HAVE_ASYNC_LDS
      __builtin_amdgcn_global_load_lds((const __attribute__((address_space(1))) void*)ga,
                                       (__attribute__((address_space(3))) void*)&ldsA[(it * 256 + wave * 64) * 8],
                                       16, 0, 0);
#else
      *reinterpret_cast<short8*>(&ldsA[slot * 8]) = ld8(ga);
#endif
    }
    #pragma unroll
    for (int it = 0; it < 4; ++it){
      int slot = tid + it * 256;
      int row = slot >> 3;
      int sc8 = (slot & 7) ^ (row & 7);
      const unsigned short* gb = &Bglob[(size_t)row * 512 + kc * 64 + sc8 * 8];
#ifdef HAVE_ASYNC_LDS
      __builtin_amdgcn_global_load_lds((const __attribute__((address_space(1))) void*)gb,
                                       (__attribute__((address_space(3))) void*)&ldsB[(it * 256 + wave * 64) * 8],
                                       16, 0, 0);
#else
      *reinterpret_cast<short8*>(&ldsB[slot * 8]) = ld8(gb);
#endif
    }
    __syncthreads();
    #pragma unroll
    for (int kk = 0; kk < 64; kk += 32){
      short8 af[4], bfr[4];
      #pragma unroll
      for (int mt = 0; mt < 4; ++mt){
        int r = R0 + mt * 16 + m16;
        af[mt] = *reinterpret_cast<const short8*>(&ldsA[r * 64 + ((((kk >> 3) + quad)) ^ (r & 7)) * 8]);
      }
      #pragma unroll
      for (int nt = 0; nt < 4; ++nt){
        int r = C0 + nt * 16 + m16;
        bfr[nt] = *reinterpret_cast<const short8*>(&ldsB[r * 64 + ((((kk >> 3) + quad)) ^ (r & 7)) * 8]);
      }
      #pragma unroll
      for (int mt = 0; mt < 4; ++mt)
        #pragma unroll
        for (int nt = 0; nt < 4; ++nt)
          acc[mt][nt] = __builtin_amdgcn_mfma_f32_16x16x32_bf16(af[mt], bfr[nt], acc[mt][nt], 0, 0, 0);
    }
    __syncthreads();
  }
  // epilogue 1: +bias, Qt -> arena as [s][d] stride 136 (B-operand layout for phase 2)
  {
    float qb[4][4];
    #pragma unroll
    for (int mt = 0; mt < 4; ++mt)
      #pragma unroll
      for (int r = 0; r < 4; ++r) qb[mt][r] = Wqb[h * 128 + R0 + mt * 16 + quad * 4 + r];
    #pragma unroll
    for (int mt = 0; mt < 4; ++mt)
      #pragma unroll
      for (int nt = 0; nt < 4; ++nt){
        int sl = C0 + nt * 16 + m16;
        short4v pk;
        #pragma unroll
        for (int r = 0; r < 4; ++r) pk[r] = (short)f2bf(acc[mt][nt][r] + qb[mt][r]);
        *reinterpret_cast<short4v*>(&Qt[sl * 136 + R0 + mt * 16 + quad * 4]) = pk;
      }
  }
  __syncthreads();                                  // B1

  // ---- phase 2: St = Kh[80x128] @ Qt[128 x 128s]; Kh fragments direct from global (L2-hot)
  f32x4 acc2[5][2];
  #pragma unroll
  for (int mt = 0; mt < 5; ++mt){ acc2[mt][0] = (f32x4){0.f,0.f,0.f,0.f}; acc2[mt][1] = (f32x4){0.f,0.f,0.f,0.f}; }
  const int cb = wave * 32;
  const unsigned short* Kb = wsK + (size_t)(bz * 77) * 512 + h * 128;
  #pragma unroll
  for (int ks = 0; ks < 4; ++ks){
    short8 bq[2];
    #pragma unroll
    for (int nt = 0; nt < 2; ++nt)
      bq[nt] = *reinterpret_cast<const short8*>(&Qt[(cb + nt * 16 + m16) * 136 + ks * 32 + quad * 8]);
    #pragma unroll
    for (int mt = 0; mt < 5; ++mt){
      int l = mt * 16 + m16;
      short8 ak = {};
      if (l < 77) ak = ld8(&Kb[(size_t)l * 512 + ks * 32 + quad * 8]);
      #pragma unroll
      for (int nt = 0; nt < 2; ++nt)
        acc2[mt][nt] = __builtin_amdgcn_mfma_f32_16x16x32_bf16(ak, bq[nt], acc2[mt][nt], 0, 0, 0);
    }
  }
  __syncthreads();                                  // B2: all Qt reads done

  // ---- softmax over l, Pt -> arena [s][l] stride 104
  {
    const float scale = 0.08838834764831845f;       // 1/sqrt(128)
    float mb[5][4];
    #pragma unroll
    for (int mt = 0; mt < 5; ++mt)
      #pragma unroll
      for (int r = 0; r < 4; ++r) mb[mt][r] = maskf[mt * 16 + quad * 4 + r];
    #pragma unroll
    for (int nt = 0; nt < 2; ++nt){
      float sv[5][4]; float mx = -3e38f;
      #pragma unroll
      for (int mt = 0; mt < 5; ++mt)
        #pragma unroll
        for (int r = 0; r < 4; ++r){
          float v = acc2[mt][nt][r] * scale + mb[mt][r];
          sv[mt][r] = v; mx = fmaxf(mx, v);
        }
      mx = fmaxf(mx, __shfl_xor(mx, 16)); mx = fmaxf(mx, __shfl_xor(mx, 32));
      float sum = 0.f;
      #pragma unroll
      for (int mt = 0; mt < 5; ++mt)
        #pragma unroll
        for (int r = 0; r < 4; ++r){ float e = __expf(sv[mt][r] - mx); sv[mt][r] = e; sum += e; }
      sum += __shfl_xor(sum, 16); sum += __shfl_xor(sum, 32);
      float inv = 1.0f / sum;
      int sl = cb + nt * 16 + m16;
      #pragma unroll
      for (int mt = 0; mt < 5; ++mt){
        short4v pk;
        #pragma unroll
        for (int r = 0; r < 4; ++r) pk[r] = (short)f2bf(sv[mt][r] * inv);
        *reinterpret_cast<short4v*>(&Pt[sl * 104 + mt * 16 + quad * 4]) = pk;
      }
      short4v z = {};
      *reinterpret_cast<short4v*>(&Pt[sl * 104 + 80 + quad * 4]) = z;  // zero l=80..95
    }
  }
  // ---- Vt -> arena+13312 [128][104] (cols 0..79 from ws, 80..95 zero)
  {
    const unsigned short* vb = wsVt + (size_t)(bz * 512 + h * 128) * 80;
    #pragma unroll
    for (int it = 0; it < 5; ++it){
      int slot = tid + it * 256;
      *reinterpret_cast<short8*>(&Vt[(slot / 10) * 104 + (slot % 10) * 8]) = ld8(&vb[(size_t)slot * 8]);
    }
    int row = tid >> 1, hf = tid & 1;
    short8 z = {};
    *reinterpret_cast<short8*>(&Vt[row * 104 + 80 + hf * 8]) = z;
  }
  __syncthreads();                                  // B3

  // ---- phase 3: Ot = Vt[128x96] @ Pt[96 x 128s]
  f32x4 acc3[4][4];
  #pragma unroll
  for (int mt = 0; mt < 4; ++mt)
    #pragma unroll
    for (int nt = 0; nt < 4; ++nt) acc3[mt][nt] = (f32x4){0.f, 0.f, 0.f, 0.f};
  #pragma unroll
  for (int ks = 0; ks < 3; ++ks){
    short8 av[4], bp[4];
    #pragma unroll
    for (int mt = 0; mt < 4; ++mt)
      av[mt] = *reinterpret_cast<const short8*>(&Vt[(R0 + mt * 16 + m16) * 104 + ks * 32 + quad * 8]);
    #pragma unroll
    for (int nt = 0; nt < 4; ++nt)
      bp[nt] = *reinterpret_cast<const short8*>(&Pt[(C0 + nt * 16 + m16) * 104 + ks * 32 + quad * 8]);
    #pragma unroll
    for (int mt = 0; mt < 4; ++mt)
      #pragma unroll
      for (int nt = 0; nt < 4; ++nt)
        acc3[mt][nt] = __builtin_amdgcn_mfma_f32_16x16x32_bf16(av[mt], bp[nt], acc3[mt][nt], 0, 0, 0);
  }
  // ---- epilogue: fp32 store + GroupNorm partials (each wave's 64x64 tile is one group)
  float sum = 0.f, ssq = 0.f;
  #pragma unroll
  for (int mt = 0; mt < 4; ++mt)
    #pragma unroll
    for (int nt = 0; nt < 4; ++nt){
      int sidx = s_glob + C0 + nt * 16 + m16;
      #pragma unroll
      for (int r = 0; r < 4; ++r){
        float v = acc3[mt][nt][r];
        sum += v; ssq += v * v;
        int d = h * 128 + R0 + mt * 16 + quad * 4 + r;
        out[(size_t)(bg * 512 + d) * 4096 + sidx] = v;
      }
    }
  #pragma unroll
  for (int off = 1; off < 64; off <<= 1){ sum += __shfl_xor(sum, off); ssq += __shfl_xor(ssq, off); }
  if (lane == 0){
    int g = h * 2 + (R0 >> 6);
    atomicAdd(&gnacc[(bg * 8 + g) * 2],     sum);
    atomicAdd(&gnacc[(bg * 8 + g) * 2 + 1], ssq);
  }
}

// ---------------------------------------------------------------- k3: GroupNorm apply, in-place on fp32 d_out
__global__ __launch_bounds__(256) void k3_gn(float* __restrict__ out,
                                             const float* __restrict__ gnacc,
                                             const float* __restrict__ gns,
                                             const float* __restrict__ gnb){
  const int bx = blockIdx.x;                 // bx = b*512 + c
  const int b = bx >> 9, c = bx & 511;
  const int g = c >> 6;
  const float s  = gnacc[(b * 8 + g) * 2];
  const float ss = gnacc[(b * 8 + g) * 2 + 1];
  const float invN = 1.f / 262144.f;
  const float mean = s * invN;
  const float var  = ss * invN - mean * mean;
  const float rstd = rsqrtf(fmaxf(var, 0.f) + 1e-5f);
  const float a  = rstd * gns[c];
  const float bb = gnb[c] - mean * a;
  const size_t base = (size_t)bx * 4096;
  #pragma unroll
  for (int p = 0; p < 4; ++p){
    size_t off = base + p * 1024 + threadIdx.x * 4;
    f32x4 v = ldf4(&out[off]);
    f32x4 o;
    #pragma unroll
    for (int j = 0; j < 4; ++j) o[j] = v[j] * a + bb;
    *reinterpret_cast<f32x4*>(&out[off]) = o;
  }
}

// ---------------------------------------------------------------- launch
extern "C" void kernel_launch(void* const* d_in, const int* in_sizes, int n_in,
                              void* d_out, int out_size, void* d_ws, size_t ws_size,
                              hipStream_t stream){
  (void)in_sizes; (void)n_in; (void)out_size;
  const float* x    = (const float*)d_in[0];
  const float* text = (const float*)d_in[1];
  const int*   am   = (const int*)d_in[2];
  const float* Wq   = (const float*)d_in[3];
  const float* Wqb  = (const float*)d_in[4];
  const float* Wk   = (const float*)d_in[5];
  const float* Wkb  = (const float*)d_in[6];
  const float* Wv   = (const float*)d_in[7];
  const float* Wvb  = (const float*)d_in[8];
  const float* gns  = (const float*)d_in[9];
  const float* gnb  = (const float*)d_in[10];
  float* out = (float*)d_out;

  auto need = [](int SB, int SLEN) -> size_t {
    return 512ull + 524288ull + (size_t)SB * 78848ull + (size_t)SB * 81920ull
         + (size_t)SB * SLEN * 1024ull;
  };
  int SB = 8, SLEN = 4096;
  if      (ws_size >= need(8, 4096)) { SB = 8; SLEN = 4096; }
  else if (ws_size >= need(4, 4096)) { SB = 4; SLEN = 4096; }
  else if (ws_size >= need(2, 4096)) { SB = 2; SLEN = 4096; }
  else if (ws_size >= need(1, 4096)) { SB = 1; SLEN = 4096; }
  else if (ws_size >= need(1, 1024)) { SB = 1; SLEN = 1024; }
  else                               { SB = 1; SLEN = 256;  }

  uint8_t* ws = (uint8_t*)d_ws;
  float*          gnacc = (float*)ws;
  unsigned short* wsWq  = (unsigned short*)(ws + 512);                  // [512][512] bf16
  unsigned short* wsK   = wsWq + 512 * 512;                             // [SB][77][512]
  unsigned short* wsVt  = wsK  + (size_t)SB * 77 * 512;                 // [SB][512][80]
  unsigned short* xT    = wsVt + (size_t)SB * 512 * 80;                 // [SB][SLEN][512]

  hipMemsetAsync(gnacc, 0, 128 * sizeof(float), stream);
  k_prep<<<256, 256, 0, stream>>>(Wq, wsWq);
  for (int b0 = 0; b0 < 8; b0 += SB){
    k1_kvproj<<<dim3(16, SB), 256, 0, stream>>>(text, Wk, Wkb, Wv, Wvb, wsK, wsVt, b0);
    for (int s_base = 0; s_base < 4096; s_base += SLEN){
      k0_transpose<<<dim3(SLEN / 64, 8, SB), 256, 0, stream>>>(x, xT, b0, s_base, SLEN);
      k2_attn<<<dim3(SLEN / 128, 4, SB), 256, 0, stream>>>(xT, wsK, wsVt, am, wsWq, Wqb,
                                                           out, gnacc, b0, s_base, SLEN);
    }
  }
  k3_gn<<<4096, 256, 0, stream>>>(out, gnacc, gns, gnb);
}

// Round 6
// 253.909 us; speedup vs baseline: 1.0630x; 1.0630x over previous
//
#include <hip/hip_runtime.h>
#include <hip/hip_bf16.h>
#include <cstdint>

// CrossAttentionMultiHead: B=8, C=512, H=W=64 (S=4096), L=77, E=768, heads=4 (dh=128), GN groups=8.
// FP32 I/O; attention_mask int32. Compute in bf16 MFMA, fp32 accum.
// R6: fat kernel (x-transpose ∪ LDS-staged K/V proj ∪ Wq->bf16 prep) so k1 latency hides behind
//     k0 bandwidth work; k2 slimmed to 34.8KB LDS (4 blocks/CU), Vt read direct from global.

typedef __attribute__((ext_vector_type(8))) short short8;
typedef __attribute__((ext_vector_type(4))) short short4v;
typedef __attribute__((ext_vector_type(4))) float f32x4;

#define DEV __device__ __forceinline__

DEV float bf2f(unsigned short u){ union{uint32_t i; float f;} x; x.i = ((uint32_t)u) << 16; return x.f; }
DEV unsigned short f2bf(float f){ __hip_bfloat16 h = __float2bfloat16(f); return *reinterpret_cast<unsigned short*>(&h); }
DEV short8 ld8(const unsigned short* p){ return *reinterpret_cast<const short8*>(p); }
DEV f32x4 ldf4(const float* p){ return *reinterpret_cast<const f32x4*>(p); }

#if defined(__has_builtin)
#if __has_builtin(__builtin_amdgcn_global_load_lds)
#define HAVE_ASYNC_LDS 1
#endif
#endif

// ---------------------------------------------------------------- fat kernel: bx<64 -> x transpose;
// bx in {64,65} -> K/V projection (uc=(bx-64)*8+by); bx==66 -> Wq fp32->bf16 prep.
__global__ __launch_bounds__(256) void k_fat(const float* __restrict__ x,
                                             unsigned short* __restrict__ xT,
                                             const float* __restrict__ text,
                                             const float* __restrict__ Wk,
                                             const float* __restrict__ Wkb,
                                             const float* __restrict__ Wv,
                                             const float* __restrict__ Wvb,
                                             unsigned short* __restrict__ wsK,
                                             unsigned short* __restrict__ wsVt,
                                             const float* __restrict__ Wq,
                                             unsigned short* __restrict__ wsWq,
                                             int b0, int s_base, int slen, int SB){
  __shared__ unsigned short U[10368];
  const int tid = threadIdx.x;
  const int bx = blockIdx.x, by = blockIdx.y, bz = blockIdx.z;
  const int bg = b0 + bz;

  if (bx < 64){
    // ---------------- transpose x[b][c][s] fp32 -> xT[bz][s-s_base][c] bf16
    if (bx * 64 >= slen) return;
    unsigned short* t = U;                       // 64x72
    const int s0 = s_base + bx * 64, c0 = by * 64;
    #pragma unroll
    for (int it = 0; it < 2; ++it){
      int slot = tid + it * 256;
      int r = slot >> 3, sg = slot & 7;
      int sw = sg ^ (r >> 3);
      const float* src = &x[((size_t)(bg * 512 + c0 + r)) * 4096 + s0 + sg * 8];
      f32x4 a = ldf4(src), b = ldf4(src + 4);
      short8 v;
      #pragma unroll
      for (int j = 0; j < 4; ++j){ v[j] = (short)f2bf(a[j]); v[j + 4] = (short)f2bf(b[j]); }
      *reinterpret_cast<short8*>(&t[r * 72 + sw * 8]) = v;
    }
    __syncthreads();
    #pragma unroll
    for (int it = 0; it < 2; ++it){
      int slot = tid + it * 256;
      int j = slot >> 3, i8 = slot & 7;
      short8 v;
      #pragma unroll
      for (int q = 0; q < 8; ++q){
        int c = i8 * 8 + q;
        int sw = (j >> 3) ^ i8;
        v[q] = (short)t[c * 72 + sw * 8 + (j & 7)];
      }
      *reinterpret_cast<short8*>(&xT[((size_t)(bz * slen) + bx * 64 + j) * 512 + c0 + i8 * 8]) = v;
    }
  } else if (bx < 66){
    // ---------------- K/V projection: out[80l x 64u] = text[80x768] @ W[u]^T, BK=64, LDS-staged
    unsigned short* At = U;                      // 80 x 72
    unsigned short* Bt = U + 5760;               // 64 x 72
    const int wave = tid >> 6, lane = tid & 63;
    const int m16 = lane & 15, quad = lane >> 4;
    const int uc = (bx - 64) * 8 + by;
    const int u0 = uc * 64;
    const bool isK = (u0 < 512);
    const float* W  = isK ? Wk  : Wv;
    const float* Wb = isK ? Wkb : Wvb;
    const int c0 = u0 & 511;
    const int c  = c0 + wave * 16 + m16;         // this lane's output column
    f32x4 acc[5];
    #pragma unroll
    for (int mt = 0; mt < 5; ++mt) acc[mt] = (f32x4){0.f, 0.f, 0.f, 0.f};
    for (int kc = 0; kc < 12; ++kc){
      const int e0 = kc * 64;
      #pragma unroll
      for (int it = 0; it < 9; ++it){
        int slot = tid + it * 256;               // 0..2303: 1280 At + 1024 Bt
        if (slot < 1280){
          int row = slot >> 4, e4 = (slot & 15) * 4;
          f32x4 v = (row < 77) ? ldf4(&text[((size_t)(bg * 77 + row)) * 768 + e0 + e4])
                               : (f32x4){0.f, 0.f, 0.f, 0.f};
          short4v o;
          #pragma unroll
          for (int j = 0; j < 4; ++j) o[j] = (short)f2bf(v[j]);
          *reinterpret_cast<short4v*>(&At[row * 72 + e4]) = o;
        } else {
          int bs = slot - 1280;
          int row = bs >> 4, e4 = (bs & 15) * 4;
          f32x4 v = ldf4(&W[((size_t)(c0 + row)) * 768 + e0 + e4]);
          short4v o;
          #pragma unroll
          for (int j = 0; j < 4; ++j) o[j] = (short)f2bf(v[j]);
          *reinterpret_cast<short4v*>(&Bt[row * 72 + e4]) = o;
        }
      }
      __syncthreads();
      #pragma unroll
      for (int kk = 0; kk < 64; kk += 32){
        short8 bf_ = *reinterpret_cast<const short8*>(&Bt[(wave * 16 + m16) * 72 + kk + quad * 8]);
        #pragma unroll
        for (int mt = 0; mt < 5; ++mt){
          short8 af_ = *reinterpret_cast<const short8*>(&At[(mt * 16 + m16) * 72 + kk + quad * 8]);
          acc[mt] = __builtin_amdgcn_mfma_f32_16x16x32_bf16(af_, bf_, acc[mt], 0, 0, 0);
        }
      }
      __syncthreads();
    }
    const float bias = Wb[c];
    if (isK){
      #pragma unroll
      for (int mt = 0; mt < 5; ++mt)
        #pragma unroll
        for (int r = 0; r < 4; ++r){
          int l = mt * 16 + quad * 4 + r;
          if (l < 77) wsK[((size_t)(bz * 77 + l)) * 512 + c] = f2bf(acc[mt][r] + bias);
        }
    } else {
      unsigned short* vr = &wsVt[((size_t)(bz * 512 + c)) * 96];
      #pragma unroll
      for (int mt = 0; mt < 5; ++mt){
        short4v pk;
        #pragma unroll
        for (int r = 0; r < 4; ++r) pk[r] = (short)f2bf(acc[mt][r] + bias);
        *reinterpret_cast<short4v*>(&vr[mt * 16 + quad * 4]) = pk;
      }
      short4v z = {};
      *reinterpret_cast<short4v*>(&vr[80 + quad * 4]) = z;   // zero l=80..95
    }
  } else {
    // ---------------- Wq fp32 -> bf16 (262144 elements over 8*SB blocks)
    const int nb = 8 * SB;
    const int p  = by + bz * 8;
    const int chunk = 262144 / nb;
    for (int i = p * chunk + tid * 4; i < (p + 1) * chunk; i += 1024){
      f32x4 v = ldf4(&Wq[i]);
      short4v o;
      #pragma unroll
      for (int j = 0; j < 4; ++j) o[j] = (short)f2bf(v[j]);
      *reinterpret_cast<short4v*>(&wsWq[i]) = o;
    }
  }
}

// ---------------------------------------------------------------- k2: fused Qproj + attention
// LDS arena (34816 B), phase-aliased:
//   phase1: A[128][64] @0 + B[128][64] @8192 (shorts)  [async-staged, source-XOR swizzle]
//   phase2: Qt[128][136] @0
//   phase3: Pt[128][104] @0; Vt fragments direct from global wsVt[c][96].
__global__ __launch_bounds__(256, 4) void k2_attn(const unsigned short* __restrict__ xT,
                                                  const unsigned short* __restrict__ wsK,
                                                  const unsigned short* __restrict__ wsVt,
                                                  const int* __restrict__ amask,
                                                  const unsigned short* __restrict__ wsWq,
                                                  const float* __restrict__ Wqb,
                                                  float* __restrict__ out,
                                                  float* __restrict__ gnacc,
                                                  int b0, int s_base, int slen){
  __shared__ unsigned short arena[17408];
  __shared__ float maskf[96];
  unsigned short* ldsA = arena;
  unsigned short* ldsB = arena + 8192;
  unsigned short* Qt   = arena;                  // stride 136
  unsigned short* Pt   = arena;                  // stride 104

  const int tid = threadIdx.x;
  const int wave = tid >> 6, lane = tid & 63;
  const int m16 = lane & 15, quad = lane >> 4;
  const int st = blockIdx.x, h = blockIdx.y, bz = blockIdx.z;
  const int bg = b0 + bz;
  const int s_glob = s_base + st * 128;
  const int R0 = (wave >> 1) * 64, C0 = (wave & 1) * 64;

  if (tid < 96){
    int l = tid;
    float mbv = -30000.f;
    if (l < 77 && amask[bg * 77 + l] != 0) mbv = 0.f;
    maskf[l] = mbv;
  }

  // ---- phase 1: Qt = Wq_h[128x512] @ x[512 x 128s], BK=64, async XOR-swizzled staging
  f32x4 acc[4][4];
  #pragma unroll
  for (int mt = 0; mt < 4; ++mt)
    #pragma unroll
    for (int nt = 0; nt < 4; ++nt) acc[mt][nt] = (f32x4){0.f, 0.f, 0.f, 0.f};
  const unsigned short* Aglob = wsWq + (size_t)(h * 128) * 512;
  const unsigned short* Bglob = xT + ((size_t)bz * slen + st * 128) * 512;
  for (int kc = 0; kc < 8; ++kc){
    #pragma unroll
    for (int it = 0; it < 4; ++it){
      int slot = tid + it * 256;
      int row = slot >> 3;
      int sc8 = (slot & 7) ^ (row & 7);
      const unsigned short* ga = &Aglob[(size_t)row * 512 + kc * 64 + sc8 * 8];
#ifdef HAVE_ASYNC_LDS
      __builtin_amdgcn_global_load_lds((const __attribute__((address_space(1))) void*)ga,
                                       (__attribute__((address_space(3))) void*)&ldsA[(it * 256 + wave * 64) * 8],
                                       16, 0, 0);
#else
      *reinterpret_cast<short8*>(&ldsA[slot * 8]) = ld8(ga);
#endif
    }
    #pragma unroll
    for (int it = 0; it < 4; ++it){
      int slot = tid + it * 256;
      int row = slot >> 3;
      int sc8 = (slot & 7) ^ (row & 7);
      const unsigned short* gb = &Bglob[(size_t)row * 512 + kc * 64 + sc8 * 8];
#ifdef HAVE_ASYNC_LDS
      __builtin_amdgcn_global_load_lds((const __attribute__((address_space(1))) void*)gb,
                                       (__attribute__((address_space(3))) void*)&ldsB[(it * 256 + wave * 64) * 8],
                                       16, 0, 0);
#else
      *reinterpret_cast<short8*>(&ldsB[slot * 8]) = ld8(gb);
#endif
    }
    __syncthreads();
    #pragma unroll
    for (int kk = 0; kk < 64; kk += 32){
      short8 af[4], bfr[4];
      #pragma unroll
      for (int mt = 0; mt < 4; ++mt){
        int r = R0 + mt * 16 + m16;
        af[mt] = *reinterpret_cast<const short8*>(&ldsA[r * 64 + (((kk >> 3) + quad) ^ (r & 7)) * 8]);
      }
      #pragma unroll
      for (int nt = 0; nt < 4; ++nt){
        int r = C0 + nt * 16 + m16;
        bfr[nt] = *reinterpret_cast<const short8*>(&ldsB[r * 64 + (((kk >> 3) + quad) ^ (r & 7)) * 8]);
      }
      #pragma unroll
      for (int mt = 0; mt < 4; ++mt)
        #pragma unroll
        for (int nt = 0; nt < 4; ++nt)
          acc[mt][nt] = __builtin_amdgcn_mfma_f32_16x16x32_bf16(af[mt], bfr[nt], acc[mt][nt], 0, 0, 0);
    }
    __syncthreads();
  }
  // epilogue 1: +bias, Qt -> arena [s][d] stride 136
  {
    float qb[4][4];
    #pragma unroll
    for (int mt = 0; mt < 4; ++mt)
      #pragma unroll
      for (int r = 0; r < 4; ++r) qb[mt][r] = Wqb[h * 128 + R0 + mt * 16 + quad * 4 + r];
    #pragma unroll
    for (int mt = 0; mt < 4; ++mt)
      #pragma unroll
      for (int nt = 0; nt < 4; ++nt){
        int sl = C0 + nt * 16 + m16;
        short4v pk;
        #pragma unroll
        for (int r = 0; r < 4; ++r) pk[r] = (short)f2bf(acc[mt][nt][r] + qb[mt][r]);
        *reinterpret_cast<short4v*>(&Qt[sl * 136 + R0 + mt * 16 + quad * 4]) = pk;
      }
  }
  __syncthreads();                                  // B1

  // ---- phase 2: St = Kh[80x128] @ Qt[128 x 128s]; Kh direct from global (L2-hot)
  f32x4 acc2[5][2];
  #pragma unroll
  for (int mt = 0; mt < 5; ++mt){ acc2[mt][0] = (f32x4){0.f,0.f,0.f,0.f}; acc2[mt][1] = (f32x4){0.f,0.f,0.f,0.f}; }
  const int cb = wave * 32;
  const unsigned short* Kb = wsK + (size_t)(bz * 77) * 512 + h * 128;
  #pragma unroll
  for (int ks = 0; ks < 4; ++ks){
    short8 bq[2];
    #pragma unroll
    for (int nt = 0; nt < 2; ++nt)
      bq[nt] = *reinterpret_cast<const short8*>(&Qt[(cb + nt * 16 + m16) * 136 + ks * 32 + quad * 8]);
    #pragma unroll
    for (int mt = 0; mt < 5; ++mt){
      int l = mt * 16 + m16;
      short8 ak = {};
      if (l < 77) ak = ld8(&Kb[(size_t)l * 512 + ks * 32 + quad * 8]);
      #pragma unroll
      for (int nt = 0; nt < 2; ++nt)
        acc2[mt][nt] = __builtin_amdgcn_mfma_f32_16x16x32_bf16(ak, bq[nt], acc2[mt][nt], 0, 0, 0);
    }
  }
  __syncthreads();                                  // B2: all Qt reads done

  // ---- softmax over l, Pt -> arena [s][l] stride 104
  {
    const float scale = 0.08838834764831845f;       // 1/sqrt(128)
    float mb[5][4];
    #pragma unroll
    for (int mt = 0; mt < 5; ++mt)
      #pragma unroll
      for (int r = 0; r < 4; ++r) mb[mt][r] = maskf[mt * 16 + quad * 4 + r];
    #pragma unroll
    for (int nt = 0; nt < 2; ++nt){
      float sv[5][4]; float mx = -3e38f;
      #pragma unroll
      for (int mt = 0; mt < 5; ++mt)
        #pragma unroll
        for (int r = 0; r < 4; ++r){
          float v = acc2[mt][nt][r] * scale + mb[mt][r];
          sv[mt][r] = v; mx = fmaxf(mx, v);
        }
      mx = fmaxf(mx, __shfl_xor(mx, 16)); mx = fmaxf(mx, __shfl_xor(mx, 32));
      float sum = 0.f;
      #pragma unroll
      for (int mt = 0; mt < 5; ++mt)
        #pragma unroll
        for (int r = 0; r < 4; ++r){ float e = __expf(sv[mt][r] - mx); sv[mt][r] = e; sum += e; }
      sum += __shfl_xor(sum, 16); sum += __shfl_xor(sum, 32);
      float inv = 1.0f / sum;
      int sl = cb + nt * 16 + m16;
      #pragma unroll
      for (int mt = 0; mt < 5; ++mt){
        short4v pk;
        #pragma unroll
        for (int r = 0; r < 4; ++r) pk[r] = (short)f2bf(sv[mt][r] * inv);
        *reinterpret_cast<short4v*>(&Pt[sl * 104 + mt * 16 + quad * 4]) = pk;
      }
      short4v z = {};
      *reinterpret_cast<short4v*>(&Pt[sl * 104 + 80 + quad * 4]) = z;  // zero l=80..95
    }
  }
  __syncthreads();                                  // B3: Pt ready for cross-wave reads

  // ---- phase 3: Ot = Vt[128x96] @ Pt[96 x 128s]; Vt fragments direct from global
  f32x4 acc3[4][4];
  #pragma unroll
  for (int mt = 0; mt < 4; ++mt)
    #pragma unroll
    for (int nt = 0; nt < 4; ++nt) acc3[mt][nt] = (f32x4){0.f, 0.f, 0.f, 0.f};
  const unsigned short* Vb = wsVt + (size_t)(bz * 512 + h * 128) * 96;
  #pragma unroll
  for (int ks = 0; ks < 3; ++ks){
    short8 av[4], bp[4];
    #pragma unroll
    for (int mt = 0; mt < 4; ++mt)
      av[mt] = ld8(&Vb[(size_t)(R0 + mt * 16 + m16) * 96 + ks * 32 + quad * 8]);
    #pragma unroll
    for (int nt = 0; nt < 4; ++nt)
      bp[nt] = *reinterpret_cast<const short8*>(&Pt[(C0 + nt * 16 + m16) * 104 + ks * 32 + quad * 8]);
    #pragma unroll
    for (int mt = 0; mt < 4; ++mt)
      #pragma unroll
      for (int nt = 0; nt < 4; ++nt)
        acc3[mt][nt] = __builtin_amdgcn_mfma_f32_16x16x32_bf16(av[mt], bp[nt], acc3[mt][nt], 0, 0, 0);
  }
  // ---- epilogue: fp32 store + GroupNorm partials (each wave's 64x64 tile is one group)
  float sum = 0.f, ssq = 0.f;
  #pragma unroll
  for (int mt = 0; mt < 4; ++mt)
    #pragma unroll
    for (int nt = 0; nt < 4; ++nt){
      int sidx = s_glob + C0 + nt * 16 + m16;
      #pragma unroll
      for (int r = 0; r < 4; ++r){
        float v = acc3[mt][nt][r];
        sum += v; ssq += v * v;
        int d = h * 128 + R0 + mt * 16 + quad * 4 + r;
        out[(size_t)(bg * 512 + d) * 4096 + sidx] = v;
      }
    }
  #pragma unroll
  for (int off = 1; off < 64; off <<= 1){ sum += __shfl_xor(sum, off); ssq += __shfl_xor(ssq, off); }
  if (lane == 0){
    int g = h * 2 + (R0 >> 6);
    atomicAdd(&gnacc[(bg * 8 + g) * 2],     sum);
    atomicAdd(&gnacc[(bg * 8 + g) * 2 + 1], ssq);
  }
}

// ---------------------------------------------------------------- k3: GroupNorm apply, in-place on fp32 d_out
__global__ __launch_bounds__(256) void k3_gn(float* __restrict__ out,
                                             const float* __restrict__ gnacc,
                                             const float* __restrict__ gns,
                                             const float* __restrict__ gnb){
  const int bx = blockIdx.x;                 // bx = b*512 + c
  const int b = bx >> 9, c = bx & 511;
  const int g = c >> 6;
  const float s  = gnacc[(b * 8 + g) * 2];
  const float ss = gnacc[(b * 8 + g) * 2 + 1];
  const float invN = 1.f / 262144.f;
  const float mean = s * invN;
  const float var  = ss * invN - mean * mean;
  const float rstd = rsqrtf(fmaxf(var, 0.f) + 1e-5f);
  const float a  = rstd * gns[c];
  const float bb = gnb[c] - mean * a;
  const size_t base = (size_t)bx * 4096;
  #pragma unroll
  for (int p = 0; p < 4; ++p){
    size_t off = base + p * 1024 + threadIdx.x * 4;
    f32x4 v = ldf4(&out[off]);
    f32x4 o;
    #pragma unroll
    for (int j = 0; j < 4; ++j) o[j] = v[j] * a + bb;
    *reinterpret_cast<f32x4*>(&out[off]) = o;
  }
}

// ---------------------------------------------------------------- launch
extern "C" void kernel_launch(void* const* d_in, const int* in_sizes, int n_in,
                              void* d_out, int out_size, void* d_ws, size_t ws_size,
                              hipStream_t stream){
  (void)in_sizes; (void)n_in; (void)out_size;
  const float* x    = (const float*)d_in[0];
  const float* text = (const float*)d_in[1];
  const int*   am   = (const int*)d_in[2];
  const float* Wq   = (const float*)d_in[3];
  const float* Wqb  = (const float*)d_in[4];
  const float* Wk   = (const float*)d_in[5];
  const float* Wkb  = (const float*)d_in[6];
  const float* Wv   = (const float*)d_in[7];
  const float* Wvb  = (const float*)d_in[8];
  const float* gns  = (const float*)d_in[9];
  const float* gnb  = (const float*)d_in[10];
  float* out = (float*)d_out;

  // ws: gnacc 512 + wsWq 512*512*2 + SB*77*512*2 (K) + SB*512*96*2 (Vt) + SB*SLEN*512*2 (xT)
  auto need = [](int SB, int SLEN) -> size_t {
    return 512ull + 524288ull + (size_t)SB * 78848ull + (size_t)SB * 98304ull
         + (size_t)SB * SLEN * 1024ull;
  };
  int SB = 8, SLEN = 4096;
  if      (ws_size >= need(8, 4096)) { SB = 8; SLEN = 4096; }
  else if (ws_size >= need(4, 4096)) { SB = 4; SLEN = 4096; }
  else if (ws_size >= need(2, 4096)) { SB = 2; SLEN = 4096; }
  else if (ws_size >= need(1, 4096)) { SB = 1; SLEN = 4096; }
  else if (ws_size >= need(1, 1024)) { SB = 1; SLEN = 1024; }
  else                               { SB = 1; SLEN = 256;  }

  uint8_t* ws = (uint8_t*)d_ws;
  float*          gnacc = (float*)ws;
  unsigned short* wsWq  = (unsigned short*)(ws + 512);                  // [512][512] bf16
  unsigned short* wsK   = wsWq + 512 * 512;                             // [SB][77][512]
  unsigned short* wsVt  = wsK  + (size_t)SB * 77 * 512;                 // [SB][512][96]
  unsigned short* xT    = wsVt + (size_t)SB * 512 * 96;                 // [SB][SLEN][512]

  hipMemsetAsync(gnacc, 0, 128 * sizeof(float), stream);
  for (int b0 = 0; b0 < 8; b0 += SB){
    for (int s_base = 0; s_base < 4096; s_base += SLEN){
      k_fat<<<dim3(67, 8, SB), 256, 0, stream>>>(x, xT, text, Wk, Wkb, Wv, Wvb,
                                                 wsK, wsVt, Wq, wsWq, b0, s_base, SLEN, SB);
      k2_attn<<<dim3(SLEN / 128, 4, SB), 256, 0, stream>>>(xT, wsK, wsVt, am, wsWq, Wqb,
                                                           out, gnacc, b0, s_base, SLEN);
    }
  }
  k3_gn<<<4096, 256, 0, stream>>>(out, gnacc, gns, gnb);
}